// Round 4
// baseline (83.735 us; speedup 1.0000x reference)
//
#include <hip/hip_runtime.h>
#include <hip/hip_bf16.h>

// Problem constants: B=128, C=21, L=2048, W=32, S=8, O=16, NW=252, NK=4032, K=672
#define Bb   128
#define Cc   21
#define Ll   2048
#define Ss   8
#define Oo   16
#define NWw  252
#define NKk  4032
#define Kk   672
#define KP   680   // LDS pitch (bf16) per o-row: conflict-light b128

typedef __attribute__((ext_vector_type(8))) short  short8;  // 8 bf16 = 4 VGPRs
typedef __attribute__((ext_vector_type(4))) float  f32x4;

static __device__ __forceinline__ unsigned short f2bf(float f) {
    union { __hip_bfloat16 h; unsigned short u; } cv;
    cv.h = __float2bfloat16(f);
    return cv.u;
}

static __device__ __forceinline__ short8 cvt8(const float4 a0, const float4 a1) {
    short8 a;
    a[0] = (short)f2bf(a0.x); a[1] = (short)f2bf(a0.y);
    a[2] = (short)f2bf(a0.z); a[3] = (short)f2bf(a0.w);
    a[4] = (short)f2bf(a1.x); a[5] = (short)f2bf(a1.y);
    a[6] = (short)f2bf(a1.z); a[7] = (short)f2bf(a1.w);
    return a;
}

// R15: in-kernel L2 warm sweep (latency-bound theory).
// Evidence ledger: R12 NT null, R14 reuse/granularity null (+32 MB L2
// traffic free), R10 transpose cost only its own HBM time -> the kernel is
// insensitive to byte count, locality locus, and run length. Only R13's
// issue-depth batching moved it (-3). => drain is latency x outstanding-
// capacity bound: per-CU miss queue (~few KB of lines) x cold-HBM latency
// (~900 cy, m126) ~= the observed ~24 us. Lever: serve the gather at
// L2-hit latency (~200 cy = 4.5x per-slot throughput). R9's cross-dispatch
// warm failed because the 268 MB re-poison fill sweeps L2 every iteration;
// so warm IN-KERNEL: phase 0 issues one dword probe per 64 B line of the
// block's x slab (672 rows x 256 B, clean row-sweep order), fire-and-
// forget (kept live by end-of-kernel asm, pinned by sched_barrier(0));
// probes and real loads L2/MSHR-merge -> worst case neutral.
// Block/MFMA structure = R14 (verified): 4 windows x 32 batches, grid
// 63x4 on XCD bid%8; w staged once to LDS (wb[11] reused to cut VGPR);
// whole A-slice batch-issued; 21-MFMA sweep; NT out stores.
__global__ __launch_bounds__(512)
void fb_fwd(const float* __restrict__ x, const float* __restrict__ w,
            float* __restrict__ out) {
    __shared__ unsigned short ws[4 * Oo * KP];   // 87.0 KB

    const int bid = blockIdx.x;
    const int r   = bid & 7;            // XCD (round-robin assumption, R4)
    const int idx = bid >> 3;           // 0..31 within XCD
    const int g   = r * 8 + (idx >> 2); // window group (4 windows each)
    if (g > 62) return;                 // 4 idle blocks on XCD 7
    const int bq   = idx & 3;           // batch quarter (32 rows)
    const int tid  = threadIdx.x;
    const int lane = tid & 63;
    const int wv   = tid >> 6;          // 0..7
    const int wm   = wv >> 2;           // m-tile within block (0..1)
    const int ww   = wv & 3;            // window within group
    const int col  = lane & 15;         // MFMA m-row (A) / n-col (B = o)
    const int quad = lane >> 4;         // k-chunk selector
    const int j    = g * 4 + ww;        // global window id
    const int s_loc = (j < NWw - 1) ? ww * 8 : 32;  // j=251: start 2016

    // ---- phase 0: L2 warm sweep. Block's x slab = 672 consecutive 8 KB
    // rows ((b*21+c) = flat row), span [g*128, g*128+256) B each. One dword
    // probe per 64 B line: 2688 lines, 512 threads x 5.25 -> 6 probes.
    const char* xslab = (const char*)x + ((size_t)bq * 672) * 8192 + g * 128;
    const int li = (tid & 3) << 6;          // line offset 0/64/128/192
    const int r0 = tid >> 2;                // row 0..127
    float p0 = *(const float*)(xslab + (size_t)(r0      ) * 8192 + li);
    float p1 = *(const float*)(xslab + (size_t)(r0 + 128) * 8192 + li);
    float p2 = *(const float*)(xslab + (size_t)(r0 + 256) * 8192 + li);
    float p3 = *(const float*)(xslab + (size_t)(r0 + 384) * 8192 + li);
    float p4 = *(const float*)(xslab + (size_t)(r0 + 512) * 8192 + li);
    float p5 = 0.f;
    if (r0 < 32) p5 = *(const float*)(xslab + (size_t)(r0 + 640) * 8192 + li);
    // Pin: probes must issue before (and never get waited by) what follows.
    __builtin_amdgcn_sched_barrier(0);

    // ---- phase 1: issue w-stage batch A (11 float4/thread, cacheable) ----
    const f32x4* wj4 = (const f32x4*)w + (size_t)g * 10752;  // 4 windows
    f32x4 wb[11];
#pragma unroll
    for (int p = 0; p < 11; ++p) wb[p] = wj4[tid + p * 512];

    // ---- phase 2: issue the whole A-slice (42 float4, all in flight) ----
    const int b = bq * 32 + wm * 16 + col;
    const float* xrow = x + ((size_t)b * Cc) * Ll + g * 32 + s_loc + quad * 8;
    float4 a0[Cc], a1[Cc];
#pragma unroll
    for (int c = 0; c < Cc; ++c) {
        a0[c] = *(const float4*)(xrow + (size_t)c * Ll);
        a1[c] = *(const float4*)(xrow + (size_t)c * Ll + 4);
    }

    // ---- phase 3: cvt + LDS-write w batch A (waits only wA loads) ----
#pragma unroll
    for (int p = 0; p < 11; ++p) {
        int t  = tid + p * 512;
        int oa = t / 168;               // (window,o) pair: 0..63
        int r4 = t - oa * 168;          // float4 index within 672-k row
        *(ushort4*)&ws[oa * KP + r4 * 4] =
            make_ushort4(f2bf(wb[p][0]), f2bf(wb[p][1]),
                         f2bf(wb[p][2]), f2bf(wb[p][3]));
    }

    // ---- phase 4: issue w batch B (10 float4, reuse wb -> VGPR cap) ----
#pragma unroll
    for (int p = 0; p < 10; ++p) wb[p] = wj4[tid + (11 + p) * 512];

    // ---- phase 5: cvt A to bf16 frags (waits x drain; wB in flight) ----
    short8 afr[Cc];
#pragma unroll
    for (int c = 0; c < Cc; ++c) afr[c] = cvt8(a0[c], a1[c]);

    // ---- phase 6: cvt + LDS-write w batch B ----
#pragma unroll
    for (int p = 0; p < 10; ++p) {
        int t  = tid + (11 + p) * 512;
        int oa = t / 168;
        int r4 = t - oa * 168;
        *(ushort4*)&ws[oa * KP + r4 * 4] =
            make_ushort4(f2bf(wb[p][0]), f2bf(wb[p][1]),
                         f2bf(wb[p][2]), f2bf(wb[p][3]));
    }

    __syncthreads();

    // ---- 21-MFMA sweep: B-tile = this wave's window (ww) ----
    const unsigned short* wrow = &ws[(ww * Oo + col) * KP + quad * 8];
    f32x4 acc = {0.f, 0.f, 0.f, 0.f};
#pragma unroll
    for (int c = 0; c < Cc; ++c)
        acc = __builtin_amdgcn_mfma_f32_16x16x32_bf16(
            afr[c], *(const short8*)(wrow + c * 32), acc, 0, 0, 0);

    // ---- C/D layout: col = lane&15, row = quad*4 + reg (verified R8) ----
    const int rbase = bq * 32 + wm * 16 + quad * 4;
    float* op = out + (size_t)rbase * NKk + j * 16 + col;
#pragma unroll
    for (int rr = 0; rr < 4; ++rr)
        __builtin_nontemporal_store(acc[rr], &op[(size_t)rr * NKk]);

    // Keep the warm probes alive (rule #17) -- placed at kernel end so the
    // implied wait is free; prevents DCE of phase 0.
    asm volatile("" :: "v"(p0), "v"(p1), "v"(p2), "v"(p3), "v"(p4), "v"(p5));
}

extern "C" void kernel_launch(void* const* d_in, const int* in_sizes, int n_in,
                              void* d_out, int out_size, void* d_ws, size_t ws_size,
                              hipStream_t stream) {
    const float* x = (const float*)d_in[0];   // (128, 21, 2048) fp32
    const float* w = (const float*)d_in[1];   // (4032, 672) fp32
    float* out = (float*)d_out;               // (128, 4032) fp32
    fb_fwd<<<dim3(256), dim3(512), 0, stream>>>(x, w, out);
}